// Round 7
// baseline (603.393 us; speedup 1.0000x reference)
//
#include <hip/hip_runtime.h>

#define SEQ 64
#define BAT 256
#define NT 32
#define EMB 256
#define HID 256
#define G3 768   // 3*HID

typedef __bf16 bf16x8 __attribute__((ext_vector_type(8)));
typedef __bf16 bf16x4 __attribute__((ext_vector_type(4)));
typedef float f32x4 __attribute__((ext_vector_type(4)));
typedef unsigned long long ulx2 __attribute__((ext_vector_type(2)));

#define GL2S 265   // gl2 row stride in 8B groups (2120 B == 18 banks -> no 4-way)
#define HQS  280   // hqb row stride in bytes   (6 banks/row -> parents collide only at dp%16==0)
// hbuf XOR swizzle at 8-elem (16B) granularity: separates rows that alias banks
// (row stride 528B == 4 dw mod 32 -> drow in {8,16,24} collided; SWZ splits all three)
#define SWZ(row) ((((row) >> 3) & 3) << 3)

__device__ __forceinline__ float sigm_fast(float x) {
    return __builtin_amdgcn_rcpf(1.f + __expf(-x));   // inf-safe
}
__device__ __forceinline__ float tanh_fast(float x) {
    return 1.f - 2.f * __builtin_amdgcn_rcpf(__expf(2.f * x) + 1.f);
}
__device__ __forceinline__ float sigm(float x) {
    x = fminf(fmaxf(x, -30.f), 30.f);
    return 1.f / (1.f + __expf(-x));
}
__device__ __forceinline__ float tanhr(float x) {
    x = fminf(fmaxf(x, -15.f), 15.f);
    float e = __expf(2.f * x);
    return (e - 1.f) / (e + 1.f);
}

// ---- K1 (merged): G = emb @ W_ih.T + b_ih ; W_hh -> fp8 frag-pack ; W_lin -> bf16 pack;
//      block 32 additionally computes h1 = gru(emb[32], 0) and tr0 = h1 @ W_lin.T + b_lin.
__global__ void k_pre(const float* __restrict__ emb, const float* __restrict__ W_ih,
                      const float* __restrict__ b_ih, const float* __restrict__ W_hh,
                      const float* __restrict__ W_lin, const float* __restrict__ b_hh,
                      const float* __restrict__ b_lin,
                      float* __restrict__ G, int2* __restrict__ Wpk8, __bf16* __restrict__ Wlpk,
                      float* __restrict__ h1, float* __restrict__ tr0)
{
    const int tid = threadIdx.x;
    const int blk = blockIdx.x;
    if (blk < 33) {
        __shared__ float es[EMB];
        __shared__ float hs[HID];
        es[tid] = emb[blk * EMB + tid];
        __syncthreads();
        const float4* e4 = (const float4*)es;
        float gv[3];
        #pragma unroll
        for (int g = 0; g < 3; ++g) {
            int c = g * HID + tid;
            const float4* w4 = (const float4*)(W_ih + c * EMB);
            float acc = b_ih[c];
            #pragma unroll 8
            for (int i = 0; i < EMB / 4; ++i) {
                float4 a = e4[i], w = w4[i];
                acc += a.x * w.x + a.y * w.y + a.z * w.z + a.w * w.w;
            }
            G[blk * G3 + c] = acc;
            gv[g] = acc;
        }
        if (blk == 32) {            // h1 (exact fp32): thread tid owns column tid
            float r = sigm(gv[0] + b_hh[tid]);
            float z = sigm(gv[1] + b_hh[HID + tid]);
            float n = tanhr(gv[2] + r * b_hh[2 * HID + tid]);
            float h = (1.f - z) * n;     // h0 = 0
            h1[tid] = h; hs[tid] = h;
            __syncthreads();
            if (tid < NT) {
                const float4* w4 = (const float4*)(W_lin + tid * HID);
                const float4* h4 = (const float4*)hs;
                float acc = b_lin[tid];
                #pragma unroll 8
                for (int i = 0; i < HID / 4; ++i) {
                    float4 a = h4[i], w = w4[i];
                    acc += a.x * w.x + a.y * w.y + a.z * w.z + a.w * w.w;
                }
                tr0[tid] = acc;
            }
        }
    } else if (blk < 129) {                 // W_hh fp8 pack: 24576 chunks
        int idx  = (blk - 33) * 256 + tid;
        int c    = idx >> 9;
        int rem  = idx & 511;
        int kt   = rem >> 6;
        int lane = rem & 63;
        int row  = c * 16 + (lane & 15);
        int col  = kt * 32 + (lane >> 4) * 8;
        const float* src = W_hh + row * 256 + col;
        int lo = __builtin_amdgcn_cvt_pk_fp8_f32(src[0], src[1], 0, 0);
        lo     = __builtin_amdgcn_cvt_pk_fp8_f32(src[2], src[3], lo, 1);
        int hi = __builtin_amdgcn_cvt_pk_fp8_f32(src[4], src[5], 0, 0);
        hi     = __builtin_amdgcn_cvt_pk_fp8_f32(src[6], src[7], hi, 1);
        Wpk8[idx] = make_int2(lo, hi);
    } else {                                // W_lin bf16 pack: 1024 chunks
        int i2   = (blk - 129) * 256 + tid;
        int nt   = i2 >> 9;
        int rem  = i2 & 511;
        int kt   = rem >> 6;
        int lane = rem & 63;
        int row  = nt * 16 + (lane & 15);
        int col  = kt * 32 + (lane >> 4) * 8;
        const float* src = W_lin + row * 256 + col;
        bf16x8 v;
        #pragma unroll
        for (int j = 0; j < 8; ++j) v[j] = (__bf16)src[j];
        *(bf16x8*)(Wlpk + i2 * 8) = v;
    }
}

// 5-stage bitonic clean on unique u64 keys (desc), within 32-lane halves
#define CLEANK32(mk, l32)                                          \
    _Pragma("unroll")                                              \
    for (int off_ = 16; off_ >= 1; off_ >>= 1) {                   \
        unsigned long long o_ = __shfl_xor((mk), off_, 64);        \
        bool up_ = ((l32) & off_) == 0;                            \
        if (up_ == (o_ > (mk))) (mk) = o_;                         \
    }

// ---- K3: one 1024-thread workgroup per batch element; fp8 W_hh register-stationary;
//          phase-overlap schedule: fp8 pack on idle waves during (e); par-independent
//          path-row MFMA (pacc) on all waves during (i2); hbuf XOR-swizzled; b_hh r/z
//          biases folded into gl2 staging.
//          5 barriers/step: (c+d1) | (e) tr+keys+pack | (f) rank | (i1) | (i2)+pacc
__global__ __launch_bounds__(1024, 1) void k_main(
    const float* __restrict__ em, const int* __restrict__ tags, const float* __restrict__ mask,
    const float* __restrict__ G, const float* __restrict__ h1w, const float* __restrict__ tr0w,
    const long* __restrict__ Wpk8, const __bf16* __restrict__ Wlpk,
    const float* __restrict__ bhhg, const float* __restrict__ bling,
    float* __restrict__ out)
{
    // gate-contiguous bf16 G (+b_hh folded for r,z): gl2[(e*GL2S+j)*4 + {r,z,n,pad}]
    __shared__ __attribute__((aligned(16))) __bf16 gl2[33 * GL2S * 4];         // 69,960 B
    __shared__ __attribute__((aligned(16))) __bf16 hbuf[2][33 * 264];          // 34,848 B bf16 state ping-pong (swizzled)
    __shared__ __attribute__((aligned(16))) unsigned char hqb[2][33 * HQS];    // 18,480 B fp8 state ping-pong (UNpermuted)
    __shared__ __attribute__((aligned(16))) __bf16 wlin[8192];                 // 16,384 B packed W_lin frags
    __shared__ __attribute__((aligned(16))) unsigned long long candk[32 * 34]; //  8,704 B sortable keys
    __shared__ __attribute__((aligned(16))) unsigned long long srtk[16 * 33];  //  4,224 B sorted key rows
    __shared__ float trs32[33];          // path row of tr
    __shared__ float em_s[SEQ * NT];
    __shared__ float mask_s[SEQ];
    __shared__ int tags_s[SEQ];
    __shared__ float scores[NT];
    __shared__ int par[NT];              // parent beam slot (for fp8 row gather)
    __shared__ int parbt[NT];            // (par<<8)|btag packed
    __shared__ float s_ps;

    const int tid = threadIdx.x;
    const int b = blockIdx.x;
    const int w = tid >> 6;
    const int lane = tid & 63;
    const int q = lane >> 4;
    const int l15 = lane & 15;
    const int j = w * 16 + l15;          // this lane's hidden column

    // ---- register-stationary W_hh fragments & biases ----
    long wreg[24];
    #pragma unroll
    for (int g = 0; g < 3; ++g)
        #pragma unroll
        for (int kt = 0; kt < 8; ++kt)
            wreg[g * 8 + kt] = Wpk8[((g * 16 + w) * 8 + kt) * 64 + lane];
    const float bn_ = bhhg[512 + j];     // r/z biases folded into gl2 staging
    float bl_ = 0.f;
    if (w < 6) bl_ = bling[(w & 1) * 16 + l15];

    // ---- prologue staging ----
    if (tid < 64) mask_s[tid] = mask[tid * BAT + b];
    else if (tid < 128) tags_s[tid - 64] = tags[(tid - 64) * BAT + b];
    else if (tid < 160) par[tid - 128] = tid - 128;
    ((bf16x8*)wlin)[tid] = ((const bf16x8*)Wlpk)[tid];
    for (int idx = tid; idx < SEQ * NT; idx += 1024)
        em_s[idx] = em[((idx >> 5) * BAT + b) * NT + (idx & 31)];
    for (int idx = tid; idx < 33 * 256; idx += 1024) {
        int row = idx >> 8, j2 = idx & 255;
        const float* gp = G + row * 768 + j2;
        bf16x4 gv;
        gv[0] = (__bf16)(gp[0]   + bhhg[j2]);        // fold b_hh_r
        gv[1] = (__bf16)(gp[256] + bhhg[256 + j2]);  // fold b_hh_z
        gv[2] = (__bf16)gp[512];                     // b_hh_n stays separate (inside r*(.))
        gv[3] = (__bf16)0.f;
        *(bf16x4*)&gl2[(row * GL2S + j2) * 4] = gv;
        hbuf[0][row * 264 + (j2 ^ SWZ(row))] = (__bf16)h1w[j2];
    }
    __syncthreads();
    // fp8 pack of initial state (same bf16->fp8 chain as the steady state)
    for (int idx = tid; idx < 33 * 32; idx += 1024) {
        int row = idx >> 5, off = (idx & 31) * 8;
        bf16x8 hv = *(const bf16x8*)&hbuf[0][row * 264 + (off ^ SWZ(row))];
        int lo = __builtin_amdgcn_cvt_pk_fp8_f32((float)hv[0], (float)hv[1], 0, 0);
        lo     = __builtin_amdgcn_cvt_pk_fp8_f32((float)hv[2], (float)hv[3], lo, 1);
        int hi = __builtin_amdgcn_cvt_pk_fp8_f32((float)hv[4], (float)hv[5], 0, 0);
        hi     = __builtin_amdgcn_cvt_pk_fp8_f32((float)hv[6], (float)hv[7], hi, 1);
        *(int2*)&hqb[0][row * HQS + off] = make_int2(lo, hi);
    }
    // ---- initial top_k of s_init = (trans0 + em0) * mask0 (rank sort, ties -> lower idx) ----
    if (tid < 32) {
        float m0 = mask_s[0];
        float v = (tr0w[tid] + em_s[tid]) * m0;
        int cnt = 0;
        for (int jj = 0; jj < 32; ++jj) {
            float vj = __shfl(v, jj, 32);
            cnt += (vj > v) || (vj == v && jj < tid);
        }
        scores[cnt] = v;
        parbt[cnt] = (cnt << 8) | tid;   // parent=cnt (identity; all rows = h1), tag=tid
    }
    if (tid == 64) {
        int t0 = tags_s[0];
        s_ps = (tr0w[t0] + em_s[t0]) * mask_s[0];
    }
    __syncthreads();

    // ---- pacc for t=1: path-row gh (par-independent). A rows 1..15 get copies of
    //      row-32 data -> junk accs in never-read output rows; row 0 is exact.
    f32x4 pacc[3];
    {
        const unsigned char* hp = &hqb[0][32 * HQS];
        #pragma unroll
        for (int g = 0; g < 3; ++g) { f32x4 z = {0.f, 0.f, 0.f, 0.f}; pacc[g] = z; }
        #pragma unroll
        for (int kt = 0; kt < 8; ++kt) {
            long a32 = *(const long*)(hp + kt * 32 + q * 8);
            #pragma unroll
            for (int g = 0; g < 3; ++g)
                pacc[g] = __builtin_amdgcn_mfma_f32_16x16x32_fp8_fp8(a32, wreg[g * 8 + kt], pacc[g], 0, 0, 0);
        }
    }

    #pragma unroll 1
    for (int t = 1; t < SEQ; ++t) {
        const int cur = (t - 1) & 1, nxt = t & 1;
        const float m_t = mask_s[t];

        // (c) gh = hidden @ W_hh.T — fp8 A rows gathered by par at READ; W from registers.
        //     Beam tiles only (48 MFMAs); path row already in pacc from the (i2) window.
        const int p0 = par[l15], p1 = par[16 + l15];
        const unsigned char* hqc = &hqb[cur][0];
        f32x4 acc[2][3];
        #pragma unroll
        for (int mt = 0; mt < 2; ++mt)
            #pragma unroll
            for (int g = 0; g < 3; ++g) {
                f32x4 z = {0.f, 0.f, 0.f, 0.f};
                acc[mt][g] = z;
            }
        #pragma unroll
        for (int kt = 0; kt < 8; ++kt) {
            const int kb = kt * 32 + q * 8;
            long af0 = *(const long*)(hqc + p0 * HQS + kb);
            long af1 = *(const long*)(hqc + p1 * HQS + kb);
            #pragma unroll
            for (int g = 0; g < 3; ++g) {
                acc[0][g] = __builtin_amdgcn_mfma_f32_16x16x32_fp8_fp8(af0, wreg[g * 8 + kt], acc[0][g], 0, 0, 0);
                acc[1][g] = __builtin_amdgcn_mfma_f32_16x16x32_fp8_fp8(af1, wreg[g * 8 + kt], acc[1][g], 0, 0, 0);
            }
        }

        // (d1) GRU elementwise; writes bf16 hbuf[nxt] only (fp8 pack overlapped into (e))
        {
            const int pt = tags_s[t - 1];
            #pragma unroll
            for (int mt = 0; mt < 2; ++mt) {
                #pragma unroll
                for (int r = 0; r < 4; ++r) {
                    const int row = mt * 16 + q * 4 + r;          // 0..31
                    const int pb = parbt[row];
                    const int e = pb & 255, src = pb >> 8;
                    bf16x4 g4 = *(const bf16x4*)&gl2[(e * GL2S + j) * 4];
                    float rr = sigm_fast((float)g4[0] + acc[mt][0][r]);
                    float zz = sigm_fast((float)g4[1] + acc[mt][1][r]);
                    float nn = tanh_fast((float)g4[2] + rr * (acc[mt][2][r] + bn_));
                    float hold = (float)hbuf[cur][src * 264 + (j ^ SWZ(src))];
                    hbuf[nxt][row * 264 + (j ^ SWZ(row))] = (__bf16)(zz * (hold - nn) + nn);
                }
            }
            if (lane < 16) {                                      // path row 32 (from pacc)
                bf16x4 g4 = *(const bf16x4*)&gl2[(pt * GL2S + j) * 4];
                float rr = sigm_fast((float)g4[0] + pacc[0][0]);
                float zz = sigm_fast((float)g4[1] + pacc[1][0]);
                float nn = tanh_fast((float)g4[2] + rr * (pacc[2][0] + bn_));
                float hold = (float)hbuf[cur][32 * 264 + (j ^ SWZ(32))];
                hbuf[nxt][32 * 264 + (j ^ SWZ(32))] = (__bf16)(zz * (hold - nn) + nn);
            }
        }
        __syncthreads();   // B1

        // (e) waves 0..5: tr = hnew @ W_lin.T + b_lin -> sortable u64 keys / trs32.
        //     waves 6..15: vectorized fp8 pack of hbuf[nxt] -> hqb[nxt] (hidden under MFMA job).
        if (w < 6) {
            const int mt = w >> 1, ntc = w & 1;
            f32x4 a2 = {0.f, 0.f, 0.f, 0.f};
            #pragma unroll
            for (int kt = 0; kt < 8; ++kt) {
                const int kk = kt * 32 + q * 8;
                bf16x8 af;
                if (mt < 2) {
                    const int row = mt * 16 + l15;
                    af = *(const bf16x8*)&hbuf[nxt][row * 264 + (kk ^ SWZ(row))];
                } else {
                    bf16x8 rv = *(const bf16x8*)&hbuf[nxt][32 * 264 + (kk ^ SWZ(32))]; // broadcast
                    bf16x8 z8 = (__bf16)0.f;
                    af = (l15 == 0) ? rv : z8;
                }
                bf16x8 bv = *(const bf16x8*)&wlin[((ntc * 8 + kt) * 64 + lane) * 8];
                a2 = __builtin_amdgcn_mfma_f32_16x16x32_bf16(af, bv, a2, 0, 0, 0);
            }
            const int colc = ntc * 16 + l15;
            if (mt < 2) {
                const float em_v = em_s[t * 32 + colc];
                #pragma unroll
                for (int r = 0; r < 4; ++r) {
                    const int row = mt * 16 + q * 4 + r;
                    float tr = a2[r] + bl_;
                    float bse = scores[parbt[row] & 255];   // faithful quirk: gather by prev TAG id
                    float v = bse + (tr + em_v) * m_t;
                    unsigned int vb = __float_as_uint(v);
                    unsigned int ov = vb ^ (0x80000000u | (unsigned int)(((int)vb) >> 31));
                    unsigned long long key =
                        ((unsigned long long)ov << 11) | (unsigned int)(1055 - (row * 32 + colc));
                    candk[row * 34 + colc] = key;
                }
            } else if (q == 0) {
                trs32[colc] = a2[0] + bl_;   // only row 32 is real
            }
        } else {
            for (int c2 = tid - 384; c2 < 33 * 32; c2 += 640) {
                int row = c2 >> 5, off = (c2 & 31) * 8;
                bf16x8 hv = *(const bf16x8*)&hbuf[nxt][row * 264 + (off ^ SWZ(row))];
                int lo = __builtin_amdgcn_cvt_pk_fp8_f32((float)hv[0], (float)hv[1], 0, 0);
                lo     = __builtin_amdgcn_cvt_pk_fp8_f32((float)hv[2], (float)hv[3], lo, 1);
                int hi = __builtin_amdgcn_cvt_pk_fp8_f32((float)hv[4], (float)hv[5], 0, 0);
                hi     = __builtin_amdgcn_cvt_pk_fp8_f32((float)hv[6], (float)hv[7], hi, 1);
                *(int2*)&hqb[nxt][row * HQS + off] = make_int2(lo, hi);
            }
        }
        __syncthreads();   // B2

        // (f) path score + exact rank of each candidate within its row pair (64) via
        //     LDS *broadcast* b128 key reads + u64 compares; direct scatter at rank.
        if (tid == 0) {
            int ct = tags_s[t];
            s_ps += (trs32[ct] + em_s[t * 32 + ct]) * m_t;
        }
        {
            const int half = lane >> 5, l32 = lane & 31;
            const int myrow = 2 * w + half;
            const unsigned long long own = candk[myrow * 34 + l32];
            const ulx2* pA = (const ulx2*)&candk[(2 * w) * 34];
            const ulx2* pB = (const ulx2*)&candk[(2 * w + 1) * 34];
            int cnt = 0;
            #pragma unroll
            for (int c = 0; c < 16; ++c) {
                ulx2 ka = pA[c];
                ulx2 kb2 = pB[c];
                cnt += (int)(ka[0] > own) + (int)(ka[1] > own)
                     + (int)(kb2[0] > own) + (int)(kb2[1] > own);
            }
            if (cnt < 32) srtk[w * 33 + cnt] = own;   // keys unique -> ranks unique
        }
        __syncthreads();   // B3

        // (i1) waves 0..3: two-level merge (16 rows -> 4), write row 4w
        if (w < 4) {
            const int half = lane >> 5, l32 = lane & 31;
            const int rA = 4 * w + 2 * half, rB = rA + 1;
            unsigned long long a = srtk[rA * 33 + l32];
            unsigned long long bb = srtk[rB * 33 + (31 - l32)];
            unsigned long long m = (a > bb) ? a : bb;
            CLEANK32(m, l32);
            unsigned long long p = __shfl_xor(m, 63, 64);
            unsigned long long m2 = (m > p) ? m : p;
            CLEANK32(m2, l32);
            if (half == 0) srtk[(4 * w) * 33 + l32] = m2;
        }
        __syncthreads();   // B4

        // (i2) wave 0: two-level merge (4 rows -> 1) -> scores/par/parbt.
        //      ALL waves: pacc for step t+1 from hqb[nxt][32] (par-independent;
        //      overlaps wave 0's serial merge on the MFMA pipe).
        if (w == 0) {
            const int half = lane >> 5, l32 = lane & 31;
            const int rA = 8 * half, rB = 8 * half + 4;
            unsigned long long a = srtk[rA * 33 + l32];
            unsigned long long bb = srtk[rB * 33 + (31 - l32)];
            unsigned long long m = (a > bb) ? a : bb;
            CLEANK32(m, l32);
            unsigned long long p = __shfl_xor(m, 63, 64);
            unsigned long long fv = (m > p) ? m : p;
            CLEANK32(fv, l32);
            if (half == 0) {
                unsigned int ov = (unsigned int)(fv >> 11);
                unsigned int bits = (ov & 0x80000000u) ? (ov ^ 0x80000000u) : ~ov;
                scores[l32] = __uint_as_float(bits);
                int fidx = 1055 - (int)(fv & 2047ULL);
                int pr = fidx >> 5, tg = fidx & 31;
                par[l32] = pr;
                parbt[l32] = (pr << 8) | tg;
            }
        }
        {
            const unsigned char* hp = &hqb[nxt][32 * HQS];
            #pragma unroll
            for (int g = 0; g < 3; ++g) { f32x4 z = {0.f, 0.f, 0.f, 0.f}; pacc[g] = z; }
            #pragma unroll
            for (int kt = 0; kt < 8; ++kt) {
                long a32 = *(const long*)(hp + kt * 32 + q * 8);
                #pragma unroll
                for (int g = 0; g < 3; ++g)
                    pacc[g] = __builtin_amdgcn_mfma_f32_16x16x32_fp8_fp8(a32, wreg[g * 8 + kt], pacc[g], 0, 0, 0);
            }
        }
        __syncthreads();   // B5
    }

    // ---- epilogue ----
    if (tid < 32) {
        float mx = scores[0];
        float ex = __expf(scores[tid] - mx);
        #pragma unroll
        for (int off = 16; off >= 1; off >>= 1) ex += __shfl_xor(ex, off, 32);
        if (tid == 0) {
            float logz = mx + logf(ex);
            atomicAdd(out, s_ps - logz);
        }
    }
}

extern "C" void kernel_launch(void* const* d_in, const int* in_sizes, int n_in,
                              void* d_out, int out_size, void* d_ws, size_t ws_size,
                              hipStream_t stream) {
    const float* emissions = (const float*)d_in[0];
    const int*   tags      = (const int*)d_in[1];
    const float* mask      = (const float*)d_in[2];
    const float* embedding = (const float*)d_in[3];
    const float* W_ih      = (const float*)d_in[4];
    const float* W_hh      = (const float*)d_in[5];
    const float* b_ih      = (const float*)d_in[6];
    const float* b_hh      = (const float*)d_in[7];
    const float* W_lin     = (const float*)d_in[8];
    const float* b_lin     = (const float*)d_in[9];
    float* out = (float*)d_out;

    char* ws = (char*)d_ws;
    float*  G    = (float*)ws;              // 33*768*4   = 101376 B
    float*  h1   = (float*)(ws + 101376);   // 256*4
    float*  tr0  = (float*)(ws + 102400);   // 32*4
    int2*   Wpk8 = (int2*)(ws + 102528);    // 24576*8    = 196608 B (fp8 frag-packed W_hh)
    __bf16* Wlpk = (__bf16*)(ws + 299136);  // 1024*8*2   = 16384 B  (bf16 frag-packed W_lin)

    hipMemsetAsync(d_out, 0, sizeof(float) * out_size, stream);
    k_pre<<<133, 256, 0, stream>>>(embedding, W_ih, b_ih, W_hh, W_lin, b_hh, b_lin,
                                   G, Wpk8, Wlpk, h1, tr0);
    k_main<<<BAT, 1024, 0, stream>>>(emissions, tags, mask, G, h1, tr0,
                                     (const long*)Wpk8, Wlpk, b_hh, b_lin, out);
}

// Round 8
// 547.862 us; speedup vs baseline: 1.1014x; 1.1014x over previous
//
#include <hip/hip_runtime.h>

#define SEQ 64
#define BAT 256
#define NT 32
#define EMB 256
#define HID 256
#define G3 768   // 3*HID

typedef __bf16 bf16x8 __attribute__((ext_vector_type(8)));
typedef __bf16 bf16x4 __attribute__((ext_vector_type(4)));
typedef float f32x4 __attribute__((ext_vector_type(4)));
typedef unsigned long long ulx2 __attribute__((ext_vector_type(2)));

#define GL2S 265   // gl2 row stride in 8B groups (2120 B == 18 banks -> no 4-way)
#define HQS  280   // hqb row stride in bytes   (6 banks/row -> parents collide only at dp%16==0)

__device__ __forceinline__ float sigm_fast(float x) {
    return __builtin_amdgcn_rcpf(1.f + __expf(-x));   // inf-safe
}
__device__ __forceinline__ float tanh_fast(float x) {
    return 1.f - 2.f * __builtin_amdgcn_rcpf(__expf(2.f * x) + 1.f);
}
__device__ __forceinline__ float sigm(float x) {
    x = fminf(fmaxf(x, -30.f), 30.f);
    return 1.f / (1.f + __expf(-x));
}
__device__ __forceinline__ float tanhr(float x) {
    x = fminf(fmaxf(x, -15.f), 15.f);
    float e = __expf(2.f * x);
    return (e - 1.f) / (e + 1.f);
}

// ---- K1 (merged): G = emb @ W_ih.T + b_ih ; W_hh -> fp8 frag-pack ; W_lin -> bf16 pack;
//      block 32 additionally computes h1 = gru(emb[32], 0) and tr0 = h1 @ W_lin.T + b_lin.
__global__ void k_pre(const float* __restrict__ emb, const float* __restrict__ W_ih,
                      const float* __restrict__ b_ih, const float* __restrict__ W_hh,
                      const float* __restrict__ W_lin, const float* __restrict__ b_hh,
                      const float* __restrict__ b_lin,
                      float* __restrict__ G, int2* __restrict__ Wpk8, __bf16* __restrict__ Wlpk,
                      float* __restrict__ h1, float* __restrict__ tr0)
{
    const int tid = threadIdx.x;
    const int blk = blockIdx.x;
    if (blk < 33) {
        __shared__ float es[EMB];
        __shared__ float hs[HID];
        es[tid] = emb[blk * EMB + tid];
        __syncthreads();
        const float4* e4 = (const float4*)es;
        float gv[3];
        #pragma unroll
        for (int g = 0; g < 3; ++g) {
            int c = g * HID + tid;
            const float4* w4 = (const float4*)(W_ih + c * EMB);
            float acc = b_ih[c];
            #pragma unroll 8
            for (int i = 0; i < EMB / 4; ++i) {
                float4 a = e4[i], w = w4[i];
                acc += a.x * w.x + a.y * w.y + a.z * w.z + a.w * w.w;
            }
            G[blk * G3 + c] = acc;
            gv[g] = acc;
        }
        if (blk == 32) {            // h1 (exact fp32): thread tid owns column tid
            float r = sigm(gv[0] + b_hh[tid]);
            float z = sigm(gv[1] + b_hh[HID + tid]);
            float n = tanhr(gv[2] + r * b_hh[2 * HID + tid]);
            float h = (1.f - z) * n;     // h0 = 0
            h1[tid] = h; hs[tid] = h;
            __syncthreads();
            if (tid < NT) {
                const float4* w4 = (const float4*)(W_lin + tid * HID);
                const float4* h4 = (const float4*)hs;
                float acc = b_lin[tid];
                #pragma unroll 8
                for (int i = 0; i < HID / 4; ++i) {
                    float4 a = h4[i], w = w4[i];
                    acc += a.x * w.x + a.y * w.y + a.z * w.z + a.w * w.w;
                }
                tr0[tid] = acc;
            }
        }
    } else if (blk < 129) {                 // W_hh fp8 pack: 24576 chunks
        int idx  = (blk - 33) * 256 + tid;
        int c    = idx >> 9;
        int rem  = idx & 511;
        int kt   = rem >> 6;
        int lane = rem & 63;
        int row  = c * 16 + (lane & 15);
        int col  = kt * 32 + (lane >> 4) * 8;
        const float* src = W_hh + row * 256 + col;
        int lo = __builtin_amdgcn_cvt_pk_fp8_f32(src[0], src[1], 0, 0);
        lo     = __builtin_amdgcn_cvt_pk_fp8_f32(src[2], src[3], lo, 1);
        int hi = __builtin_amdgcn_cvt_pk_fp8_f32(src[4], src[5], 0, 0);
        hi     = __builtin_amdgcn_cvt_pk_fp8_f32(src[6], src[7], hi, 1);
        Wpk8[idx] = make_int2(lo, hi);
    } else {                                // W_lin bf16 pack: 1024 chunks
        int i2   = (blk - 129) * 256 + tid;
        int nt   = i2 >> 9;
        int rem  = i2 & 511;
        int kt   = rem >> 6;
        int lane = rem & 63;
        int row  = nt * 16 + (lane & 15);
        int col  = kt * 32 + (lane >> 4) * 8;
        const float* src = W_lin + row * 256 + col;
        bf16x8 v;
        #pragma unroll
        for (int j = 0; j < 8; ++j) v[j] = (__bf16)src[j];
        *(bf16x8*)(Wlpk + i2 * 8) = v;
    }
}

// 5-stage bitonic clean on unique u64 keys (desc), within 32-lane halves
#define CLEANK32(mk, l32)                                          \
    _Pragma("unroll")                                              \
    for (int off_ = 16; off_ >= 1; off_ >>= 1) {                   \
        unsigned long long o_ = __shfl_xor((mk), off_, 64);        \
        bool up_ = ((l32) & off_) == 0;                            \
        if (up_ == (o_ > (mk))) (mk) = o_;                         \
    }

// ---- K3: one 1024-thread workgroup per batch element; fp8 W_hh register-stationary;
//          phase-overlap schedule (r6 skeleton): fp8 pack on idle waves during (i1);
//          par-independent path-row MFMA (pacc) on all waves during (i2); b_hh r/z
//          folded into gl2; path-row tr tile replaced by a single dot (wave 4 in (e)).
//          5 barriers/step: (c+d1) | (e) tr+keys+dot | (f) rank | (i1)+pack | (i2)+pacc
__global__ __launch_bounds__(1024, 1) void k_main(
    const float* __restrict__ em, const int* __restrict__ tags, const float* __restrict__ mask,
    const float* __restrict__ G, const float* __restrict__ h1w, const float* __restrict__ tr0w,
    const long* __restrict__ Wpk8, const __bf16* __restrict__ Wlpk,
    const float* __restrict__ Wlg, const float* __restrict__ bhhg,
    const float* __restrict__ bling, float* __restrict__ out)
{
    // gate-contiguous bf16 G (+b_hh folded for r,z): gl2[(e*GL2S+j)*4 + {r,z,n,pad}]
    __shared__ __attribute__((aligned(16))) __bf16 gl2[33 * GL2S * 4];         // 69,960 B
    __shared__ __attribute__((aligned(16))) __bf16 hbuf[2][33 * 264];          // 34,848 B bf16 state ping-pong
    __shared__ __attribute__((aligned(16))) unsigned char hqb[2][33 * HQS];    // 18,480 B fp8 state ping-pong (UNpermuted)
    __shared__ __attribute__((aligned(16))) __bf16 wlin[8192];                 // 16,384 B packed W_lin frags
    __shared__ __attribute__((aligned(16))) unsigned long long candk[32 * 34]; //  8,704 B sortable keys
    __shared__ __attribute__((aligned(16))) unsigned long long srtk[16 * 33];  //  4,224 B sorted key rows
    __shared__ float trs_sc;             // tr[ct] of the path row (the only element ever used)
    __shared__ float em_s[SEQ * NT];
    __shared__ float mask_s[SEQ];
    __shared__ int tags_s[SEQ];
    __shared__ float scores[NT];
    __shared__ int par[NT];              // parent beam slot (for fp8 row gather)
    __shared__ int parbt[NT];            // (par<<8)|btag packed
    __shared__ float s_ps;

    const int tid = threadIdx.x;
    const int b = blockIdx.x;
    const int w = tid >> 6;
    const int lane = tid & 63;
    const int q = lane >> 4;
    const int l15 = lane & 15;
    const int j = w * 16 + l15;          // this lane's hidden column

    // ---- register-stationary W_hh fragments & biases ----
    long wreg[24];
    #pragma unroll
    for (int g = 0; g < 3; ++g)
        #pragma unroll
        for (int kt = 0; kt < 8; ++kt)
            wreg[g * 8 + kt] = Wpk8[((g * 16 + w) * 8 + kt) * 64 + lane];
    const float bn_ = bhhg[512 + j];     // r/z biases folded into gl2 staging
    float bl_ = 0.f;
    if (w < 4) bl_ = bling[(w & 1) * 16 + l15];

    // ---- prologue staging ----
    if (tid < 64) mask_s[tid] = mask[tid * BAT + b];
    else if (tid < 128) tags_s[tid - 64] = tags[(tid - 64) * BAT + b];
    else if (tid < 160) par[tid - 128] = tid - 128;
    ((bf16x8*)wlin)[tid] = ((const bf16x8*)Wlpk)[tid];
    for (int idx = tid; idx < SEQ * NT; idx += 1024)
        em_s[idx] = em[((idx >> 5) * BAT + b) * NT + (idx & 31)];
    for (int idx = tid; idx < 33 * 256; idx += 1024) {
        int row = idx >> 8, j2 = idx & 255;
        const float* gp = G + row * 768 + j2;
        bf16x4 gv;
        gv[0] = (__bf16)(gp[0]   + bhhg[j2]);        // fold b_hh_r
        gv[1] = (__bf16)(gp[256] + bhhg[256 + j2]);  // fold b_hh_z
        gv[2] = (__bf16)gp[512];                     // b_hh_n stays separate (inside r*(.))
        gv[3] = (__bf16)0.f;
        *(bf16x4*)&gl2[(row * GL2S + j2) * 4] = gv;
        hbuf[0][row * 264 + j2] = (__bf16)h1w[j2];
    }
    __syncthreads();
    // fp8 pack of initial state (same bf16->fp8 chain as the steady state)
    for (int idx = tid; idx < 33 * 32; idx += 1024) {
        int row = idx >> 5, off = (idx & 31) * 8;
        bf16x8 hv = *(const bf16x8*)&hbuf[0][row * 264 + off];
        int lo = __builtin_amdgcn_cvt_pk_fp8_f32((float)hv[0], (float)hv[1], 0, 0);
        lo     = __builtin_amdgcn_cvt_pk_fp8_f32((float)hv[2], (float)hv[3], lo, 1);
        int hi = __builtin_amdgcn_cvt_pk_fp8_f32((float)hv[4], (float)hv[5], 0, 0);
        hi     = __builtin_amdgcn_cvt_pk_fp8_f32((float)hv[6], (float)hv[7], hi, 1);
        *(int2*)&hqb[0][row * HQS + off] = make_int2(lo, hi);
    }
    // ---- initial top_k of s_init = (trans0 + em0) * mask0 (rank sort, ties -> lower idx) ----
    if (tid < 32) {
        float m0 = mask_s[0];
        float v = (tr0w[tid] + em_s[tid]) * m0;
        int cnt = 0;
        for (int jj = 0; jj < 32; ++jj) {
            float vj = __shfl(v, jj, 32);
            cnt += (vj > v) || (vj == v && jj < tid);
        }
        scores[cnt] = v;
        parbt[cnt] = (cnt << 8) | tid;   // parent=cnt (identity; all rows = h1), tag=tid
    }
    if (tid == 64) {
        int t0 = tags_s[0];
        s_ps = (tr0w[t0] + em_s[t0]) * mask_s[0];
    }
    __syncthreads();

    // ---- pacc for t=1: path-row gh (par-independent). A rows 1..15 get copies of
    //      row-32 data -> junk accs in never-read output rows; row 0 is exact.
    f32x4 pacc[3];
    {
        const unsigned char* hp = &hqb[0][32 * HQS];
        #pragma unroll
        for (int g = 0; g < 3; ++g) { f32x4 z = {0.f, 0.f, 0.f, 0.f}; pacc[g] = z; }
        #pragma unroll
        for (int kt = 0; kt < 8; ++kt) {
            long a32 = *(const long*)(hp + kt * 32 + q * 8);
            #pragma unroll
            for (int g = 0; g < 3; ++g)
                pacc[g] = __builtin_amdgcn_mfma_f32_16x16x32_fp8_fp8(a32, wreg[g * 8 + kt], pacc[g], 0, 0, 0);
        }
    }

    #pragma unroll 1
    for (int t = 1; t < SEQ; ++t) {
        const int cur = (t - 1) & 1, nxt = t & 1;
        const float m_t = mask_s[t];

        // (c) gh = hidden @ W_hh.T — fp8 A rows gathered by par at READ; W from registers.
        //     Beam tiles only (48 MFMAs); path row already in pacc from the (i2) window.
        const int p0 = par[l15], p1 = par[16 + l15];
        const unsigned char* hqc = &hqb[cur][0];
        f32x4 acc[2][3];
        #pragma unroll
        for (int mt = 0; mt < 2; ++mt)
            #pragma unroll
            for (int g = 0; g < 3; ++g) {
                f32x4 z = {0.f, 0.f, 0.f, 0.f};
                acc[mt][g] = z;
            }
        #pragma unroll
        for (int kt = 0; kt < 8; ++kt) {
            const int kb = kt * 32 + q * 8;
            long af0 = *(const long*)(hqc + p0 * HQS + kb);
            long af1 = *(const long*)(hqc + p1 * HQS + kb);
            #pragma unroll
            for (int g = 0; g < 3; ++g) {
                acc[0][g] = __builtin_amdgcn_mfma_f32_16x16x32_fp8_fp8(af0, wreg[g * 8 + kt], acc[0][g], 0, 0, 0);
                acc[1][g] = __builtin_amdgcn_mfma_f32_16x16x32_fp8_fp8(af1, wreg[g * 8 + kt], acc[1][g], 0, 0, 0);
            }
        }

        // (d1) GRU elementwise; writes bf16 hbuf[nxt] only (fp8 pack overlapped into (i1))
        {
            const int pt = tags_s[t - 1];
            #pragma unroll
            for (int mt = 0; mt < 2; ++mt) {
                #pragma unroll
                for (int r = 0; r < 4; ++r) {
                    const int row = mt * 16 + q * 4 + r;          // 0..31
                    const int pb = parbt[row];
                    const int e = pb & 255, src = pb >> 8;
                    bf16x4 g4 = *(const bf16x4*)&gl2[(e * GL2S + j) * 4];
                    float rr = sigm_fast((float)g4[0] + acc[mt][0][r]);
                    float zz = sigm_fast((float)g4[1] + acc[mt][1][r]);
                    float nn = tanh_fast((float)g4[2] + rr * (acc[mt][2][r] + bn_));
                    float hold = (float)hbuf[cur][src * 264 + j];
                    hbuf[nxt][row * 264 + j] = (__bf16)(zz * (hold - nn) + nn);
                }
            }
            if (lane < 16) {                                      // path row 32 (from pacc)
                bf16x4 g4 = *(const bf16x4*)&gl2[(pt * GL2S + j) * 4];
                float rr = sigm_fast((float)g4[0] + pacc[0][0]);
                float zz = sigm_fast((float)g4[1] + pacc[1][0]);
                float nn = tanh_fast((float)g4[2] + rr * (pacc[2][0] + bn_));
                float hold = (float)hbuf[cur][32 * 264 + j];
                hbuf[nxt][32 * 264 + j] = (__bf16)(zz * (hold - nn) + nn);
            }
        }
        __syncthreads();   // B1

        // (e) waves 0..3: beam tr = hnew @ W_lin.T + b_lin -> sortable u64 keys.
        //     wave 4: path-row tr[ct] via direct bf16 dot (only element ever used).
        if (w < 4) {
            const int mt = w >> 1, ntc = w & 1;
            f32x4 a2 = {0.f, 0.f, 0.f, 0.f};
            #pragma unroll
            for (int kt = 0; kt < 8; ++kt) {
                const int kk = kt * 32 + q * 8;
                bf16x8 af = *(const bf16x8*)&hbuf[nxt][(mt * 16 + l15) * 264 + kk];
                bf16x8 bv = *(const bf16x8*)&wlin[((ntc * 8 + kt) * 64 + lane) * 8];
                a2 = __builtin_amdgcn_mfma_f32_16x16x32_bf16(af, bv, a2, 0, 0, 0);
            }
            const int colc = ntc * 16 + l15;
            const float em_v = em_s[t * 32 + colc];
            #pragma unroll
            for (int r = 0; r < 4; ++r) {
                const int row = mt * 16 + q * 4 + r;
                float tr = a2[r] + bl_;
                float bse = scores[parbt[row] & 255];   // faithful quirk: gather by prev TAG id
                float v = bse + (tr + em_v) * m_t;
                unsigned int vb = __float_as_uint(v);
                unsigned int ov = vb ^ (0x80000000u | (unsigned int)(((int)vb) >> 31));
                unsigned long long key =
                    ((unsigned long long)ov << 11) | (unsigned int)(1055 - (row * 32 + colc));
                candk[row * 34 + colc] = key;
            }
        } else if (w == 4) {
            const int ct = tags_s[t];
            bf16x4 h4 = *(const bf16x4*)&hbuf[nxt][32 * 264 + lane * 4];
            float4 wl = *(const float4*)&Wlg[ct * 256 + lane * 4];
            float partial = (float)h4[0] * (float)(__bf16)wl.x
                          + (float)h4[1] * (float)(__bf16)wl.y
                          + (float)h4[2] * (float)(__bf16)wl.z
                          + (float)h4[3] * (float)(__bf16)wl.w;
            #pragma unroll
            for (int off = 32; off >= 1; off >>= 1) partial += __shfl_xor(partial, off, 64);
            if (lane == 0) trs_sc = partial + bling[ct];
        }
        __syncthreads();   // B2

        // (f) path score + exact rank of each candidate within its row pair (64) via
        //     LDS *broadcast* b128 key reads + u64 compares; direct scatter at rank.
        if (tid == 0) {
            int ct = tags_s[t];
            s_ps += (trs_sc + em_s[t * 32 + ct]) * m_t;
        }
        {
            const int half = lane >> 5, l32 = lane & 31;
            const int myrow = 2 * w + half;
            const unsigned long long own = candk[myrow * 34 + l32];
            const ulx2* pA = (const ulx2*)&candk[(2 * w) * 34];
            const ulx2* pB = (const ulx2*)&candk[(2 * w + 1) * 34];
            int cnt = 0;
            #pragma unroll
            for (int c = 0; c < 16; ++c) {
                ulx2 ka = pA[c];
                ulx2 kb2 = pB[c];
                cnt += (int)(ka[0] > own) + (int)(ka[1] > own)
                     + (int)(kb2[0] > own) + (int)(kb2[1] > own);
            }
            if (cnt < 32) srtk[w * 33 + cnt] = own;   // keys unique -> ranks unique
        }
        __syncthreads();   // B3

        // (i1) waves 0..3: two-level merge (16 rows -> 4), write row 4w.
        //      waves 4..15: vectorized fp8 pack of hbuf[nxt] -> hqb[nxt] (overlapped).
        if (w < 4) {
            const int half = lane >> 5, l32 = lane & 31;
            const int rA = 4 * w + 2 * half, rB = rA + 1;
            unsigned long long a = srtk[rA * 33 + l32];
            unsigned long long bb = srtk[rB * 33 + (31 - l32)];
            unsigned long long m = (a > bb) ? a : bb;
            CLEANK32(m, l32);
            unsigned long long p = __shfl_xor(m, 63, 64);
            unsigned long long m2 = (m > p) ? m : p;
            CLEANK32(m2, l32);
            if (half == 0) srtk[(4 * w) * 33 + l32] = m2;
        } else {
            for (int c2 = tid - 256; c2 < 33 * 32; c2 += 768) {
                int row = c2 >> 5, off = (c2 & 31) * 8;
                bf16x8 hv = *(const bf16x8*)&hbuf[nxt][row * 264 + off];
                int lo = __builtin_amdgcn_cvt_pk_fp8_f32((float)hv[0], (float)hv[1], 0, 0);
                lo     = __builtin_amdgcn_cvt_pk_fp8_f32((float)hv[2], (float)hv[3], lo, 1);
                int hi = __builtin_amdgcn_cvt_pk_fp8_f32((float)hv[4], (float)hv[5], 0, 0);
                hi     = __builtin_amdgcn_cvt_pk_fp8_f32((float)hv[6], (float)hv[7], hi, 1);
                *(int2*)&hqb[nxt][row * HQS + off] = make_int2(lo, hi);
            }
        }
        __syncthreads();   // B4

        // (i2) wave 0: two-level merge (4 rows -> 1) -> scores/par/parbt.
        //      ALL waves: pacc for step t+1 from hqb[nxt][32] (par-independent;
        //      overlaps wave 0's serial merge on the MFMA pipe).
        if (w == 0) {
            const int half = lane >> 5, l32 = lane & 31;
            const int rA = 8 * half, rB = 8 * half + 4;
            unsigned long long a = srtk[rA * 33 + l32];
            unsigned long long bb = srtk[rB * 33 + (31 - l32)];
            unsigned long long m = (a > bb) ? a : bb;
            CLEANK32(m, l32);
            unsigned long long p = __shfl_xor(m, 63, 64);
            unsigned long long fv = (m > p) ? m : p;
            CLEANK32(fv, l32);
            if (half == 0) {
                unsigned int ov = (unsigned int)(fv >> 11);
                unsigned int bits = (ov & 0x80000000u) ? (ov ^ 0x80000000u) : ~ov;
                scores[l32] = __uint_as_float(bits);
                int fidx = 1055 - (int)(fv & 2047ULL);
                int pr = fidx >> 5, tg = fidx & 31;
                par[l32] = pr;
                parbt[l32] = (pr << 8) | tg;
            }
        }
        {
            const unsigned char* hp = &hqb[nxt][32 * HQS];
            #pragma unroll
            for (int g = 0; g < 3; ++g) { f32x4 z = {0.f, 0.f, 0.f, 0.f}; pacc[g] = z; }
            #pragma unroll
            for (int kt = 0; kt < 8; ++kt) {
                long a32 = *(const long*)(hp + kt * 32 + q * 8);
                #pragma unroll
                for (int g = 0; g < 3; ++g)
                    pacc[g] = __builtin_amdgcn_mfma_f32_16x16x32_fp8_fp8(a32, wreg[g * 8 + kt], pacc[g], 0, 0, 0);
            }
        }
        __syncthreads();   // B5
    }

    // ---- epilogue ----
    if (tid < 32) {
        float mx = scores[0];
        float ex = __expf(scores[tid] - mx);
        #pragma unroll
        for (int off = 16; off >= 1; off >>= 1) ex += __shfl_xor(ex, off, 32);
        if (tid == 0) {
            float logz = mx + logf(ex);
            atomicAdd(out, s_ps - logz);
        }
    }
}

extern "C" void kernel_launch(void* const* d_in, const int* in_sizes, int n_in,
                              void* d_out, int out_size, void* d_ws, size_t ws_size,
                              hipStream_t stream) {
    const float* emissions = (const float*)d_in[0];
    const int*   tags      = (const int*)d_in[1];
    const float* mask      = (const float*)d_in[2];
    const float* embedding = (const float*)d_in[3];
    const float* W_ih      = (const float*)d_in[4];
    const float* W_hh      = (const float*)d_in[5];
    const float* b_ih      = (const float*)d_in[6];
    const float* b_hh      = (const float*)d_in[7];
    const float* W_lin     = (const float*)d_in[8];
    const float* b_lin     = (const float*)d_in[9];
    float* out = (float*)d_out;

    char* ws = (char*)d_ws;
    float*  G    = (float*)ws;              // 33*768*4   = 101376 B
    float*  h1   = (float*)(ws + 101376);   // 256*4
    float*  tr0  = (float*)(ws + 102400);   // 32*4
    int2*   Wpk8 = (int2*)(ws + 102528);    // 24576*8    = 196608 B (fp8 frag-packed W_hh)
    __bf16* Wlpk = (__bf16*)(ws + 299136);  // 1024*8*2   = 16384 B  (bf16 frag-packed W_lin)

    hipMemsetAsync(d_out, 0, sizeof(float) * out_size, stream);
    k_pre<<<133, 256, 0, stream>>>(embedding, W_ih, b_ih, W_hh, W_lin, b_hh, b_lin,
                                   G, Wpk8, Wlpk, h1, tr0);
    k_main<<<BAT, 1024, 0, stream>>>(emissions, tags, mask, G, h1, tr0,
                                     (const long*)Wpk8, Wlpk, W_lin, b_hh, b_lin, out);
}